// Round 1
// baseline (351.608 us; speedup 1.0000x reference)
//
#include <hip/hip_runtime.h>

// FastAttention (Performer linear attention), MI355X gfx950.
// B=4 L=4096 H=16 D=E=64 M=256, all fp32 in/out. bf16 MFMA internally.
//
// Pipeline:
//   hipMemsetAsync(ws KV/Ksum region, 0)
//   k1_kv : KVt[bh][e][m] += sum_l phi(k)[l,m]*v[l,e] ; Ksum[bh][m] (fp32 atomics)
//   k3_out: out[l,e] = (phi(q)[l,:] @ KV) / (phi(q)[l,:] . (Ksum+1e-6))
// phi(x) = relu((x*D^-0.25) @ P^T) + 1e-3 ; scale folded into P bf16 conversion.
//
// R1 (this round): latency-bound fix. 512-thread blocks (16 waves/CU resident,
// was 8), register prefetch of next 64-row tile under the GEMM phase (T14),
// k3 barriers 4->2 per iter (per-thread den), vt stride 66 (conflict-free
// scalar column reads).

#define LL 4096
#define HH 16
#define DD 64
#define EE 64
#define MM 256
#define SCALE 0.35355339059327378f  // 64^-0.25

typedef __attribute__((ext_vector_type(8))) __bf16 bf8v;
typedef __attribute__((ext_vector_type(4))) __bf16 bf4v;
typedef __attribute__((ext_vector_type(2))) __bf16 bf2v;
typedef __attribute__((ext_vector_type(4))) float f4v;

__device__ __forceinline__ __bf16 f2bf(float f) {
  // round-to-nearest-even fp32 -> bf16 (no NaN handling needed; inputs are normal)
  union { float f; unsigned u; } x; x.f = f;
  unsigned r = (x.u + 0x7FFFu + ((x.u >> 16) & 1u)) >> 16;
  union { unsigned short s; __bf16 b; } y; y.s = (unsigned short)r;
  return y.b;
}

#define MFMA16(a, b, c) __builtin_amdgcn_mfma_f32_16x16x32_bf16(a, b, c, 0, 0, 0)

// ws layout (float elements): [ KVt: 64 bh * 64 e * 256 m ][ Ksum: 64 bh * 256 m ]
#define KV_ELEMS (64 * 64 * 256)
#define KSUM_OFF KV_ELEMS
#define WS_ZERO_BYTES ((size_t)(KV_ELEMS + 64 * 256) * 4)

// ---------------------------------------------------------------------------
// Kernel 1: build KV and Ksum.
// grid (8 chunks, 64 bh), 512 threads (8 waves). Each block: 512 rows, 8 iters
// of 64. Per wave: owns m-band [32*w, 32*w+32).
// Loop: {write LDS from prefetch regs; sync; issue loads it+1; GEMM1; GEMM2; sync}
// ---------------------------------------------------------------------------
__global__ __launch_bounds__(512, 4)
void k1_kv(const float* __restrict__ kin, const float* __restrict__ vin,
           const float* __restrict__ pin, float* __restrict__ ws) {
  __shared__ __bf16 kt[64 * 72];    // k tile, natural [l][d], stride 72 (b128-aligned)
  __shared__ __bf16 vt[64 * 66];    // v tile, natural [l][e], stride 66 (scalar reads conflict-free)
  __shared__ __bf16 kft[256 * 72];  // phi(k)^T [m][l], stride 72 (per-wave band, self-RAW only)

  const int tid = threadIdx.x;
  const int w = tid >> 6;     // wave 0..7, owns m-band 32*w
  const int lane = tid & 63;
  const int qd = lane >> 4;   // quad
  const int nn = lane & 15;
  const int bh = blockIdx.y;
  const int b = bh >> 4, h = bh & 15;
  const int l0 = blockIdx.x * 512;

  const size_t bhbase = (size_t)b * LL * HH * DD + (size_t)h * DD;
  const int srow = tid >> 3;        // 0..63
  const int scol = (tid & 7) * 8;   // 0,8,..,56

  // ---- prefetch tile 0 (issued before P-fragment setup to hide latency) ----
  const float* gk = kin + bhbase + (size_t)(l0 + srow) * (HH * DD) + scol;
  const float* gv = vin + bhbase + (size_t)(l0 + srow) * (HH * DD) + scol;
  f4v pk0 = ((const f4v*)gk)[0], pk1 = ((const f4v*)gk)[1];
  f4v pv0 = ((const f4v*)gv)[0], pv1 = ((const f4v*)gv)[1];

  // P fragments (B-operand of GEMM1): rows m = 32*w + mt*16 + nn, k d = c*32+qd*8+j.
  bf8v pf[2][2];
#pragma unroll
  for (int mt = 0; mt < 2; ++mt) {
    const float* pr = pin + (size_t)(32 * w + mt * 16 + nn) * DD;
#pragma unroll
    for (int c = 0; c < 2; ++c) {
      bf8v t;
#pragma unroll
      for (int j = 0; j < 8; ++j) t[j] = f2bf(pr[c * 32 + qd * 8 + j] * SCALE);
      pf[mt][c] = t;
    }
  }

  f4v acc[2][4];  // KV accum: [mt][et], C rows m = 32w+mt*16+4qd+r, cols e = et*16+nn
#pragma unroll
  for (int i = 0; i < 2; ++i)
#pragma unroll
    for (int j = 0; j < 4; ++j) acc[i][j] = (f4v){0.f, 0.f, 0.f, 0.f};
  float ksum[2] = {0.f, 0.f};  // per-lane partial for m = 32w+mt*16+nn

  for (int it = 0; it < 8; ++it) {
    // ---- write staged tile from prefetch regs ----
    {
      bf8v wk;
#pragma unroll
      for (int j = 0; j < 4; ++j) { wk[j] = f2bf(pk0[j]); wk[j + 4] = f2bf(pk1[j]); }
      *(bf8v*)&kt[srow * 72 + scol] = wk;
      bf2v x0 = {f2bf(pv0[0]), f2bf(pv0[1])};
      bf2v x1 = {f2bf(pv0[2]), f2bf(pv0[3])};
      bf2v x2 = {f2bf(pv1[0]), f2bf(pv1[1])};
      bf2v x3 = {f2bf(pv1[2]), f2bf(pv1[3])};
      *(bf2v*)&vt[srow * 66 + scol]     = x0;
      *(bf2v*)&vt[srow * 66 + scol + 2] = x1;
      *(bf2v*)&vt[srow * 66 + scol + 4] = x2;
      *(bf2v*)&vt[srow * 66 + scol + 6] = x3;
    }
    __syncthreads();

    // ---- issue next tile's global loads (in flight across GEMM1+GEMM2) ----
    if (it < 7) {
      gk += 64 * HH * DD; gv += 64 * HH * DD;
      pk0 = ((const f4v*)gk)[0]; pk1 = ((const f4v*)gk)[1];
      pv0 = ((const f4v*)gv)[0]; pv1 = ((const f4v*)gv)[1];
    }

    // ---- GEMM1: C[l][m] = kt . P^T ; phi ; ksum ; write kft[m][l] (own band) ----
#pragma unroll
    for (int lt = 0; lt < 4; ++lt) {
      bf8v a0 = *(const bf8v*)&kt[(lt * 16 + nn) * 72 + qd * 8];
      bf8v a1 = *(const bf8v*)&kt[(lt * 16 + nn) * 72 + 32 + qd * 8];
#pragma unroll
      for (int mt = 0; mt < 2; ++mt) {
        f4v cc = (f4v){0.f, 0.f, 0.f, 0.f};
        cc = MFMA16(a0, pf[mt][0], cc);
        cc = MFMA16(a1, pf[mt][1], cc);
        // lane holds rows l = lt*16+4qd+r, col m = 32w+mt*16+nn
        bf4v pk;
#pragma unroll
        for (int r = 0; r < 4; ++r) {
          float ph = fmaxf(cc[r], 0.f) + 1e-3f;
          ksum[mt] += ph;  // fp32, pre-rounding
          pk[r] = f2bf(ph);
        }
        *(bf4v*)&kft[(32 * w + mt * 16 + nn) * 72 + lt * 16 + qd * 4] = pk;
      }
    }

    // ---- GEMM2: acc[m][e] += kft(own band) . v  (same-wave kft RAW) ----
#pragma unroll
    for (int c = 0; c < 2; ++c) {
      bf8v af0 = *(const bf8v*)&kft[(32 * w + nn) * 72 + c * 32 + qd * 8];
      bf8v af1 = *(const bf8v*)&kft[(32 * w + 16 + nn) * 72 + c * 32 + qd * 8];
#pragma unroll
      for (int et = 0; et < 4; ++et) {
        bf8v bv;  // B[k=l][n=e]: column of vt (8 scalar reads, stride 66 -> conflict-free)
#pragma unroll
        for (int j = 0; j < 8; ++j) bv[j] = vt[(c * 32 + qd * 8 + j) * 66 + et * 16 + nn];
        acc[0][et] = MFMA16(af0, bv, acc[0][et]);
        acc[1][et] = MFMA16(af1, bv, acc[1][et]);
      }
    }
    __syncthreads();
  }

  // ---- epilogue: atomic-accumulate KVt[bh][e][m] and Ksum[bh][m] ----
  float* kvb = ws + (size_t)bh * (64 * 256);
#pragma unroll
  for (int mt = 0; mt < 2; ++mt)
#pragma unroll
    for (int et = 0; et < 4; ++et) {
#pragma unroll
      for (int r = 0; r < 4; ++r) {
        int m = 32 * w + mt * 16 + 4 * qd + r;
        int e = et * 16 + nn;
        atomicAdd(&kvb[e * 256 + m], acc[mt][et][r]);
      }
    }
#pragma unroll
  for (int mt = 0; mt < 2; ++mt) {
    float s = ksum[mt];
    s += __shfl_xor(s, 16, 64);
    s += __shfl_xor(s, 32, 64);
    if (lane < 16) atomicAdd(&ws[KSUM_OFF + bh * 256 + 32 * w + mt * 16 + lane], s);
  }
}

// ---------------------------------------------------------------------------
// Kernel 3: out = (phi(q) @ KV) / (phi(q) . (Ksum+1e-6)).
// grid (8, 64), 512 threads (8 waves = (wm 0..3, wl 0..1)), 8 iters of 64 rows.
// wm: m-band 64 (GEMM3') / e-band 16 (GEMM4, kvf in regs); wl: lt-pair split.
// 2 barriers/iter (was 4): den summed per-thread from denp partials at store.
// ---------------------------------------------------------------------------
__global__ __launch_bounds__(512, 4)
void k3_out(const float* __restrict__ qin, const float* __restrict__ pin,
            const float* __restrict__ ws, float* __restrict__ out) {
  __shared__ __bf16 qt[64 * 72];    // q tile natural [l][d]
  __shared__ __bf16 qf[64 * 264];   // phi(q) [l][m], stride 264 (bank-even, b128-aligned)
  __shared__ float denp[256];       // den partials [wm][l]
  __shared__ float ksume[256];      // Ksum + 1e-6 (fp32)

  const int tid = threadIdx.x;
  const int w = tid >> 6;
  const int wm = w & 3;       // m-band / e-band
  const int wl = w >> 2;      // lt-pair
  const int lane = tid & 63;
  const int qd = lane >> 4;
  const int nn = lane & 15;
  const int bh = blockIdx.y;
  const int b = bh >> 4, h = bh & 15;
  const int l0 = blockIdx.x * 512;
  const int lt0 = 2 * wl;

  const size_t bhbase = (size_t)b * LL * HH * DD + (size_t)h * DD;
  const int srow = tid >> 3;
  const int scol = (tid & 7) * 8;

  // ---- prefetch q tile 0 ----
  const float* gq = qin + bhbase + (size_t)(l0 + srow) * (HH * DD) + scol;
  f4v pq0 = ((const f4v*)gq)[0], pq1 = ((const f4v*)gq)[1];

  // P fragments (A-operand of GEMM3': rows m = 64*wm + mt*16 + nn).
  bf8v pf[4][2];
#pragma unroll
  for (int mt = 0; mt < 4; ++mt) {
    const float* pr = pin + (size_t)(64 * wm + mt * 16 + nn) * DD;
#pragma unroll
    for (int c = 0; c < 2; ++c) {
      bf8v t;
#pragma unroll
      for (int j = 0; j < 8; ++j) t[j] = f2bf(pr[c * 32 + qd * 8 + j] * SCALE);
      pf[mt][c] = t;
    }
  }

  // KV fragments: B[k=m][n=e], e = 16*wm + nn, m = c*32 + qd*8 + j (dup across wl).
  const float* kvb = ws + (size_t)bh * (64 * 256);
  bf8v kvf[8];
#pragma unroll
  for (int c = 0; c < 8; ++c) {
    const float* src = kvb + (size_t)(16 * wm + nn) * 256 + c * 32 + qd * 8;
    bf8v t;
#pragma unroll
    for (int j = 0; j < 8; ++j) t[j] = f2bf(src[j]);
    kvf[c] = t;
  }

  if (tid < 256) ksume[tid] = ws[KSUM_OFF + bh * 256 + tid] + 1e-6f;  // Z_EPS

  for (int it = 0; it < 8; ++it) {
    // ---- write staged q tile from prefetch regs ----
    {
      bf8v wq;
#pragma unroll
      for (int j = 0; j < 4; ++j) { wq[j] = f2bf(pq0[j]); wq[j + 4] = f2bf(pq1[j]); }
      *(bf8v*)&qt[srow * 72 + scol] = wq;
    }
    __syncthreads();  // also covers ksume/kvf first use

    // ---- issue next tile's loads (in flight across GEMM3'+GEMM4) ----
    if (it < 7) {
      gq += 64 * HH * DD;
      pq0 = ((const f4v*)gq)[0]; pq1 = ((const f4v*)gq)[1];
    }

    // ---- GEMM3': C[m][l] = P . q^T ; phi ; den partial ; write qf[l][m] ----
#pragma unroll
    for (int li = 0; li < 2; ++li) {
      const int lt = lt0 + li;
      bf8v b0 = *(const bf8v*)&qt[(lt * 16 + nn) * 72 + qd * 8];
      bf8v b1 = *(const bf8v*)&qt[(lt * 16 + nn) * 72 + 32 + qd * 8];
      float dpart = 0.f;  // lane's col l = lt*16+nn
#pragma unroll
      for (int mt = 0; mt < 4; ++mt) {
        f4v cc = (f4v){0.f, 0.f, 0.f, 0.f};
        cc = MFMA16(pf[mt][0], b0, cc);
        cc = MFMA16(pf[mt][1], b1, cc);
        // lane holds rows m = 64wm+mt*16+4qd+r, col l = lt*16+nn
        bf4v pk;
#pragma unroll
        for (int r = 0; r < 4; ++r) {
          float ph = fmaxf(cc[r], 0.f) + 1e-3f;
          dpart += ph * ksume[64 * wm + mt * 16 + 4 * qd + r];
          pk[r] = f2bf(ph);
        }
        *(bf4v*)&qf[(lt * 16 + nn) * 264 + 64 * wm + mt * 16 + 4 * qd] = pk;
      }
      dpart += __shfl_xor(dpart, 16, 64);
      dpart += __shfl_xor(dpart, 32, 64);
      if (lane < 16) denp[wm * 64 + lt * 16 + lane] = dpart;
    }
    __syncthreads();

    // ---- GEMM4: out[l][e] = qf . KV, scale by 1/den, store ----
#pragma unroll
    for (int li = 0; li < 2; ++li) {
      const int lt = lt0 + li;
      f4v co = (f4v){0.f, 0.f, 0.f, 0.f};
#pragma unroll
      for (int c = 0; c < 8; ++c) {
        bf8v af = *(const bf8v*)&qf[(lt * 16 + nn) * 264 + c * 32 + qd * 8];
        co = MFMA16(af, kvf[c], co);
      }
      // den[r] = sum over wm partials (broadcast f4v reads, no barrier needed)
      f4v d0 = *(const f4v*)&denp[0 * 64 + lt * 16 + 4 * qd];
      f4v d1 = *(const f4v*)&denp[1 * 64 + lt * 16 + 4 * qd];
      f4v d2 = *(const f4v*)&denp[2 * 64 + lt * 16 + 4 * qd];
      f4v d3 = *(const f4v*)&denp[3 * 64 + lt * 16 + 4 * qd];
#pragma unroll
      for (int r = 0; r < 4; ++r) {
        int lrel = lt * 16 + 4 * qd + r;
        int labs = l0 + it * 64 + lrel;
        float rden = 1.f / (d0[r] + d1[r] + d2[r] + d3[r]);
        out[((size_t)((size_t)b * LL + labs) * HH + h) * EE + 16 * wm + nn] =
            co[r] * rden;
      }
    }
    // no loop-end barrier: next iter's qt write is fenced by sync1 before any
    // wave's GEMM3' reads it; denp/qf readers all passed sync2 of this iter.
  }
}

extern "C" void kernel_launch(void* const* d_in, const int* in_sizes, int n_in,
                              void* d_out, int out_size, void* d_ws, size_t ws_size,
                              hipStream_t stream) {
  (void)in_sizes; (void)n_in; (void)out_size;
  const float* q = (const float*)d_in[0];
  const float* k = (const float*)d_in[1];
  const float* v = (const float*)d_in[2];
  const float* p = (const float*)d_in[3];
  float* ws = (float*)d_ws;
  float* out = (float*)d_out;

  if (ws_size < WS_ZERO_BYTES) return;  // need ~4.3 MB scratch for KV/Ksum

  hipMemsetAsync(d_ws, 0, WS_ZERO_BYTES, stream);
  dim3 grid(8, 64), blk(512);
  k1_kv<<<grid, blk, 0, stream>>>(k, v, p, ws);
  k3_out<<<grid, blk, 0, stream>>>(q, p, ws, out);
}